// Round 11
// baseline (125.077 us; speedup 1.0000x reference)
//
#include <hip/hip_runtime.h>
#include <hip/hip_cooperative_groups.h>
#include <math.h>

namespace cg = cooperative_groups;

static constexpr int GD  = 8;       // GAUGE_DIM
static constexpr int DG  = 28;      // dim of so(8)
static constexpr int BN_TOT = 1024; // B*N
static constexpr int TI  = 4;       // rows i per block in pair phase
static constexpr float EPSF = 1e-8f;

__host__ __device__ constexpr int gidx(int a, int b) {  // a < b
    return a * 7 - a * (a - 1) / 2 + (b - a - 1);
}

// agent-scope coherent store/load: per-access visibility across XCDs
// (R3 showed plain stores + __threadfence are NOT enough on this chip)
__device__ __forceinline__ void ast(float* p, float v) {
    __hip_atomic_store(p, v, __ATOMIC_RELAXED, __HIP_MEMORY_SCOPE_AGENT);
}
__device__ __forceinline__ float ald(const float* p) {
    return __hip_atomic_load(const_cast<float*>(p), __ATOMIC_RELAXED,
                             __HIP_MEMORY_SCOPE_AGENT);
}

// ---- Single cooperative kernel: exp -> (grid sync) -> pairs -> (grid sync)
// ---- -> final reduce.  512 blocks x 256 threads (co-resident: 2/CU).
__global__ __launch_bounds__(256, 4) void fused_kernel(
    const float* __restrict__ mu, const float* __restrict__ sigma,
    const float* __restrict__ phi,
    float* E, float* ET, float* s0_arr, float* s1_arr,
    float* out) {
    cg::grid_group grid = cg::this_grid();
    const int bid  = blockIdx.x;
    const int tid  = threadIdx.x;
    const int wid  = tid >> 6;
    const int lane = tid & 63;

    __shared__ float ls[4][64];        // phase A transpose staging
    __shared__ float shE[TI * 64];     // phase B: block's 4 E_i matrices
    __shared__ float sh[TI][4][2];     // phase B partial sums
    __shared__ float shf[4];           // phase C reduce

    // ================= Phase A: E_n = exp5(M(phi_n)), blocks 0..255 ========
    // E  [n][64]  row-major   (pair phase: E_i, contiguous per block)
    // ET [k][1024] transposed (pair phase: E_j, lane-coalesced)
    if (bid < 256) {
        const int n0 = bid << 2;
        const int n  = n0 + wid;                 // row in [0,1024)
        const int p  = lane >> 3, q = lane & 7;

        const float pv = (lane < DG) ? phi[(size_t)n * DG + lane] : 0.0f;
        const int  idx = (p < q) ? gidx(p, q) : ((p > q) ? gidx(q, p) : 0);
        const float sgn = (p < q) ? 1.0f : ((p > q) ? -1.0f : 0.0f);
        const float a = sgn * __shfl(pv, idx);   // A[p][q]

        float P = a;                              // running power A^k
        float R = ((p == q) ? 1.0f : 0.0f) + a;   // I + A
        const float invk[4] = {0.5f, 1.0f/3.0f, 0.25f, 0.2f};
#pragma unroll
        for (int k = 0; k < 4; ++k) {             // orders 2..5
            float np = 0.0f;
#pragma unroll
            for (int r8 = 0; r8 < 8; ++r8) {
                np += __shfl(P, (lane & 56) + r8) * __shfl(a, (r8 << 3) + (lane & 7));
            }
            P = np * invk[k];
            R += P;
        }
        ast(&E[(size_t)n * 64 + lane], R);

        ls[wid][lane] = R;
        __syncthreads();
        const int k  = tid >> 2;                  // element 0..63
        const int dn = tid & 3;                   // row offset 0..3
        ast(&ET[(size_t)k * BN_TOT + n0 + dn], ls[dn][k]);
    }

    grid.sync();

    // ================= Phase B: pair work, all 512 blocks ===================
    // block = (i-group of 4 rows) x (j-half of 256);  1 j per thread.
    {
        const int ig   = bid >> 1;          // i-group [0,256)
        const int half = bid & 1;
        const int i0   = ig << 2;           // first row (TI | 512: batch intact)
        const int base = i0 & ~511;         // b*512
        const int gj   = base + (half << 8) + tid;

        // per-thread j loads (plain: inputs are read-only)
        float muj[GD], rcj[GD], ldj;
        {
            const float4* p4 = reinterpret_cast<const float4*>(mu + (size_t)gj * GD);
            float4 v0 = p4[0], v1 = p4[1];
            muj[0]=v0.x; muj[1]=v0.y; muj[2]=v0.z; muj[3]=v0.w;
            muj[4]=v1.x; muj[5]=v1.y; muj[6]=v1.z; muj[7]=v1.w;
        }
        {
            const float4* p4 = reinterpret_cast<const float4*>(sigma + (size_t)gj * GD);
            float4 v0 = p4[0], v1 = p4[1];
            float s[GD] = {v0.x, v0.y, v0.z, v0.w, v1.x, v1.y, v1.z, v1.w};
            float prod = 1.0f;
#pragma unroll
            for (int k = 0; k < GD; ++k) {
                const float sp = s[k] + EPSF;
                rcj[k] = __builtin_amdgcn_rcpf(sp);
                prod *= sp;
            }
            ldj = __logf(prod);   // one log (validated R7-R10, absmax 0)
        }

        // E_j row -> 64 VGPRs, lane-coalesced coherent loads
        float ej[64];
#pragma unroll
        for (int k = 0; k < 64; ++k) ej[k] = ald(&ET[(size_t)k * BN_TOT + gj]);

        // block's 4 E_i matrices -> LDS (one coherent load per thread;
        // rows i0..i0+3 are contiguous in row-major E)
        shE[tid] = ald(&E[(size_t)i0 * 64 + tid]);
        __syncthreads();

#pragma unroll 1
        for (int ii = 0; ii < TI; ++ii) {
            const int row = i0 + ii;
            const float* Ei   = &shE[ii * 64];           // LDS broadcast
            const float* mrow = mu + (size_t)row * GD;    // uniform input
            const float* srow = sigma + (size_t)row * GD; // uniform input

            // t = E_i * mu_j
            float t[GD];
#pragma unroll
            for (int p = 0; p < GD; ++p) {
                float tp = 0.0f;
#pragma unroll
                for (int q = 0; q < GD; ++q) tp = fmaf(Ei[(p << 3) + q], muj[q], tp);
                t[p] = tp;
            }
            // r = E_j^T * t
            float r[GD] = {0,0,0,0,0,0,0,0};
#pragma unroll
            for (int p = 0; p < GD; ++p) {
                const float tp = t[p];
#pragma unroll
                for (int c = 0; c < GD; ++c) r[c] = fmaf(ej[(p << 3) + c], tp, r[c]);
            }

            // klb = kl + 0.5*ld_i (uniform shift; corrected in phase C)
            float acc = 0.0f;
#pragma unroll
            for (int k = 0; k < GD; ++k) {
                const float df = r[k] - mrow[k];
                acc += (srow[k] + df * df) * rcj[k];
            }
            const float klb = 0.5f * (acc - 8.0f + ldj);

            // raw softmax partial (no max pass: diag kl~0, validated R5-R10)
            const float e  = __expf(-klb);
            float s0 = e;
            float s1 = klb * e;
#pragma unroll
            for (int off = 32; off > 0; off >>= 1) {
                s0 += __shfl_xor(s0, off);
                s1 += __shfl_xor(s1, off);
            }
            if ((tid & 63) == 0) {
                sh[ii][wid][0] = s0;
                sh[ii][wid][1] = s1;
            }
        }
        __syncthreads();
        if (tid < TI * 2) {
            const int ii = tid >> 1, c = tid & 1;
            const float v = sh[ii][0][c] + sh[ii][1][c] + sh[ii][2][c] + sh[ii][3][c];
            float* dst = c ? s1_arr : s0_arr;
            ast(&dst[(size_t)(i0 + ii) * 2 + half], v);
        }
    }

    grid.sync();

    // ================= Phase C: final reduce, block 0 =======================
    if (bid == 0) {
        float v = 0.0f;
#pragma unroll
        for (int c = 0; c < 4; ++c) {
            const int r = tid + (c << 8);   // rows tid, tid+256, tid+512, tid+768
            const float S0 = ald(&s0_arr[2*r]) + ald(&s0_arr[2*r + 1]);
            const float S1 = ald(&s1_arr[2*r]) + ald(&s1_arr[2*r + 1]);

            float prod = 1.0f, ssum = 0.f, msum = 0.f;
#pragma unroll
            for (int k = 0; k < GD; ++k) {
                const float s  = sigma[(size_t)r * GD + k];
                const float mm = mu[(size_t)r * GD + k];
                prod *= (s + EPSF);
                ssum += s;
                msum += mm * mm;
            }
            const float ld = __logf(prod);
            const float f_align = S1 / S0 - 0.5f * ld;
            // -entropy + 0.1*kl_prior ; K*log(2*pi*e) = 22.703016531274763
            const float cterm = -0.5f * (22.70301653127476f + ld)
                              + 0.05f * (ssum + msum - 8.0f - ld);
            v += cterm + f_align;
        }
#pragma unroll
        for (int off = 32; off > 0; off >>= 1) v += __shfl_xor(v, off);
        if ((tid & 63) == 0) shf[wid] = v;
        __syncthreads();
        if (tid == 0)
            out[0] = (shf[0] + shf[1] + shf[2] + shf[3]) * (1.0f / (float)BN_TOT);
    }
}

extern "C" void kernel_launch(void* const* d_in, const int* in_sizes, int n_in,
                              void* d_out, int out_size, void* d_ws, size_t ws_size,
                              hipStream_t stream) {
    const float* mu    = (const float*)d_in[0];
    const float* sigma = (const float*)d_in[1];
    const float* phi   = (const float*)d_in[2];
    float* out = (float*)d_out;
    float* ws  = (float*)d_ws;

    float* E      = ws;            // 65536 floats (row-major)
    float* ET     = ws + 65536;    // 65536 floats (transposed)
    float* s0_arr = ws + 131072;   // 2048
    float* s1_arr = ws + 133120;   // 2048

    void* args[] = {(void*)&mu, (void*)&sigma, (void*)&phi,
                    (void*)&E, (void*)&ET, (void*)&s0_arr, (void*)&s1_arr,
                    (void*)&out};
    hipLaunchCooperativeKernel((const void*)fused_kernel,
                               dim3(512), dim3(256), args, 0, stream);
}

// Round 12
// 78.496 us; speedup vs baseline: 1.5934x; 1.5934x over previous
//
#include <hip/hip_runtime.h>
#include <math.h>

static constexpr int GD  = 8;       // GAUGE_DIM
static constexpr int DG  = 28;      // dim of so(8)
static constexpr int BN_TOT = 1024; // B*N
static constexpr int TI  = 2;       // rows i per block in pair phase
static constexpr int NBLK = 2 * BN_TOT / TI;   // 1024 blocks
static constexpr float EPSF = 1e-8f;

__host__ __device__ constexpr int gidx(int a, int b) {  // a < b
    return a * 7 - a * (a - 1) / 2 + (b - a - 1);
}

// agent-scope coherent ops: verified correct cross-XCD in R11 (absmax 0.0)
__device__ __forceinline__ void ast(float* p, float v) {
    __hip_atomic_store(p, v, __ATOMIC_RELAXED, __HIP_MEMORY_SCOPE_AGENT);
}
__device__ __forceinline__ float ald(const float* p) {
    return __hip_atomic_load(const_cast<float*>(p), __ATOMIC_RELAXED,
                             __HIP_MEMORY_SCOPE_AGENT);
}

// ---- Single fused kernel; manual arrive/spin barrier (NOT cg::grid.sync,
// ---- which measured ~40-50us/sync in R11). Counters pre-zeroed by a
// ---- hipMemsetAsync node in the same graph.
// Grid 1024 x 256, launch_bounds(256,4) => 4 blocks/CU, whole grid co-resident.
__global__ __launch_bounds__(256, 4) void fused_kernel(
    const float* __restrict__ mu, const float* __restrict__ sigma,
    const float* __restrict__ phi,
    float* E, float* ET, float* s0_arr, float* s1_arr,
    unsigned int* ctr,        // ctr[0] = exp-phase arrivals, ctr[1] = done blocks
    float* out) {
    const int bid  = blockIdx.x;
    const int tid  = threadIdx.x;
    const int wid  = tid >> 6;
    const int lane = tid & 63;

    __shared__ float ls[4][64];        // phase A transpose staging
    __shared__ float shE[TI * 64];     // phase B: block's E_i matrices
    __shared__ float sh[TI][4][2];     // phase B partial sums
    __shared__ float shf[4];           // phase C reduce
    __shared__ int   sh_last;

    // ================= Phase A: E_n = exp5(M(phi_n)), blocks 0..255 ========
    if (bid < 256) {
        const int n0 = bid << 2;
        const int n  = n0 + wid;                 // row in [0,1024)
        const int p  = lane >> 3, q = lane & 7;

        const float pv = (lane < DG) ? phi[(size_t)n * DG + lane] : 0.0f;
        const int  idx = (p < q) ? gidx(p, q) : ((p > q) ? gidx(q, p) : 0);
        const float sgn = (p < q) ? 1.0f : ((p > q) ? -1.0f : 0.0f);
        const float a = sgn * __shfl(pv, idx);   // A[p][q]

        float P = a;                              // running power A^k
        float R = ((p == q) ? 1.0f : 0.0f) + a;   // I + A
        const float invk[4] = {0.5f, 1.0f/3.0f, 0.25f, 0.2f};
#pragma unroll
        for (int k = 0; k < 4; ++k) {             // orders 2..5
            float np = 0.0f;
#pragma unroll
            for (int r8 = 0; r8 < 8; ++r8) {
                np += __shfl(P, (lane & 56) + r8) * __shfl(a, (r8 << 3) + (lane & 7));
            }
            P = np * invk[k];
            R += P;
        }
        ast(&E[(size_t)n * 64 + lane], R);

        ls[wid][lane] = R;
        __syncthreads();
        const int k  = tid >> 2;                  // element 0..63
        const int dn = tid & 3;                   // row offset 0..3
        ast(&ET[(size_t)k * BN_TOT + n0 + dn], ls[dn][k]);
    }

    // ================= Barrier: wait for all 256 producer blocks ============
    __syncthreads();   // drain this block's stores (vmcnt(0) before s_barrier)
    if (tid == 0) {
        if (bid < 256)
            __hip_atomic_fetch_add(&ctr[0], 1u, __ATOMIC_RELEASE,
                                   __HIP_MEMORY_SCOPE_AGENT);
        while (__hip_atomic_load(&ctr[0], __ATOMIC_ACQUIRE,
                                 __HIP_MEMORY_SCOPE_AGENT) < 256u)
            __builtin_amdgcn_s_sleep(2);
    }
    __syncthreads();

    // ================= Phase B: pair work, all 1024 blocks ==================
    // block = (i-group of TI rows) x (j-half of 256); 1 j per thread.
    {
        const int ig   = bid >> 1;          // i-group [0,512)
        const int half = bid & 1;
        const int i0   = ig * TI;           // first row (TI | 512: batch intact)
        const int base = i0 & ~511;         // b*512
        const int gj   = base + (half << 8) + tid;

        // per-thread j loads (read-only inputs: plain loads)
        float muj[GD], rcj[GD], ldj;
        {
            const float4* p4 = reinterpret_cast<const float4*>(mu + (size_t)gj * GD);
            float4 v0 = p4[0], v1 = p4[1];
            muj[0]=v0.x; muj[1]=v0.y; muj[2]=v0.z; muj[3]=v0.w;
            muj[4]=v1.x; muj[5]=v1.y; muj[6]=v1.z; muj[7]=v1.w;
        }
        {
            const float4* p4 = reinterpret_cast<const float4*>(sigma + (size_t)gj * GD);
            float4 v0 = p4[0], v1 = p4[1];
            float s[GD] = {v0.x, v0.y, v0.z, v0.w, v1.x, v1.y, v1.z, v1.w};
            float prod = 1.0f;
#pragma unroll
            for (int k = 0; k < GD; ++k) {
                const float sp = s[k] + EPSF;
                rcj[k] = __builtin_amdgcn_rcpf(sp);
                prod *= sp;
            }
            ldj = __logf(prod);   // one log (validated R7-R11, absmax 0)
        }

        // E_j row -> registers, lane-coalesced coherent loads
        float ej[64];
#pragma unroll
        for (int k = 0; k < 64; ++k) ej[k] = ald(&ET[(size_t)k * BN_TOT + gj]);

        // block's TI E_i matrices -> LDS
        if (tid < TI * 64) shE[tid] = ald(&E[(size_t)i0 * 64 + tid]);
        __syncthreads();

#pragma unroll 1
        for (int ii = 0; ii < TI; ++ii) {
            const int row = i0 + ii;
            const float* Ei   = &shE[ii * 64];            // LDS broadcast
            const float* mrow = mu + (size_t)row * GD;    // uniform input
            const float* srow = sigma + (size_t)row * GD; // uniform input

            // t = E_i * mu_j
            float t[GD];
#pragma unroll
            for (int p = 0; p < GD; ++p) {
                float tp = 0.0f;
#pragma unroll
                for (int q = 0; q < GD; ++q) tp = fmaf(Ei[(p << 3) + q], muj[q], tp);
                t[p] = tp;
            }
            // r = E_j^T * t
            float r[GD] = {0,0,0,0,0,0,0,0};
#pragma unroll
            for (int p = 0; p < GD; ++p) {
                const float tp = t[p];
#pragma unroll
                for (int c = 0; c < GD; ++c) r[c] = fmaf(ej[(p << 3) + c], tp, r[c]);
            }

            // klb = kl + 0.5*ld_i (uniform shift; corrected in phase C)
            float acc = 0.0f;
#pragma unroll
            for (int k = 0; k < GD; ++k) {
                const float df = r[k] - mrow[k];
                acc += (srow[k] + df * df) * rcj[k];
            }
            const float klb = 0.5f * (acc - 8.0f + ldj);

            // raw softmax partial (no max pass: diag kl~0, validated R5-R11)
            const float e  = __expf(-klb);
            float s0 = e;
            float s1 = klb * e;
#pragma unroll
            for (int off = 32; off > 0; off >>= 1) {
                s0 += __shfl_xor(s0, off);
                s1 += __shfl_xor(s1, off);
            }
            if ((tid & 63) == 0) {
                sh[ii][wid][0] = s0;
                sh[ii][wid][1] = s1;
            }
        }
        __syncthreads();
        if (tid < TI * 2) {
            const int ii = tid >> 1, c = tid & 1;
            const float v = sh[ii][0][c] + sh[ii][1][c] + sh[ii][2][c] + sh[ii][3][c];
            float* dst = c ? s1_arr : s0_arr;
            ast(&dst[(size_t)(i0 + ii) * 2 + half], v);
        }
    }

    // ================= Phase C: last block reduces (no barrier) =============
    __syncthreads();   // drain this block's partial stores
    if (tid == 0) {
        const unsigned int old =
            __hip_atomic_fetch_add(&ctr[1], 1u, __ATOMIC_ACQ_REL,
                                   __HIP_MEMORY_SCOPE_AGENT);
        sh_last = (old == (unsigned int)(NBLK - 1)) ? 1 : 0;
    }
    __syncthreads();
    if (sh_last) {
        float v = 0.0f;
#pragma unroll
        for (int c = 0; c < 4; ++c) {
            const int r = tid + (c << 8);   // rows tid, +256, +512, +768
            const float S0 = ald(&s0_arr[2*r]) + ald(&s0_arr[2*r + 1]);
            const float S1 = ald(&s1_arr[2*r]) + ald(&s1_arr[2*r + 1]);

            float prod = 1.0f, ssum = 0.f, msum = 0.f;
#pragma unroll
            for (int k = 0; k < GD; ++k) {
                const float s  = sigma[(size_t)r * GD + k];
                const float mm = mu[(size_t)r * GD + k];
                prod *= (s + EPSF);
                ssum += s;
                msum += mm * mm;
            }
            const float ld = __logf(prod);
            const float f_align = S1 / S0 - 0.5f * ld;
            // -entropy + 0.1*kl_prior ; K*log(2*pi*e) = 22.703016531274763
            const float cterm = -0.5f * (22.70301653127476f + ld)
                              + 0.05f * (ssum + msum - 8.0f - ld);
            v += cterm + f_align;
        }
#pragma unroll
        for (int off = 32; off > 0; off >>= 1) v += __shfl_xor(v, off);
        if ((tid & 63) == 0) shf[wid] = v;
        __syncthreads();
        if (tid == 0)
            out[0] = (shf[0] + shf[1] + shf[2] + shf[3]) * (1.0f / (float)BN_TOT);
    }
}

extern "C" void kernel_launch(void* const* d_in, const int* in_sizes, int n_in,
                              void* d_out, int out_size, void* d_ws, size_t ws_size,
                              hipStream_t stream) {
    const float* mu    = (const float*)d_in[0];
    const float* sigma = (const float*)d_in[1];
    const float* phi   = (const float*)d_in[2];
    float* out = (float*)d_out;
    float* ws  = (float*)d_ws;

    float*        E      = ws;            // 65536 floats (row-major)
    float*        ET     = ws + 65536;    // 65536 floats (transposed)
    float*        s0_arr = ws + 131072;   // 2048
    float*        s1_arr = ws + 133120;   // 2048
    unsigned int* ctr    = (unsigned int*)(ws + 135168);  // 2 uints

    hipMemsetAsync(ctr, 0, 2 * sizeof(unsigned int), stream);
    void* args[] = {(void*)&mu, (void*)&sigma, (void*)&phi,
                    (void*)&E, (void*)&ET, (void*)&s0_arr, (void*)&s1_arr,
                    (void*)&ctr, (void*)&out};
    hipLaunchKernelGGL(fused_kernel, dim3(NBLK), dim3(256), 0, stream,
                       mu, sigma, phi, E, ET, s0_arr, s1_arr, ctr, out);
    (void)args;
}

// Round 13
// 26.480 us; speedup vs baseline: 4.7234x; 2.9643x over previous
//
#include <hip/hip_runtime.h>
#include <math.h>

static constexpr int GD  = 8;       // GAUGE_DIM
static constexpr int DG  = 28;      // dim of so(8)
static constexpr int BN_TOT = 1024; // B*N
static constexpr int TI  = 4;       // rows i per vfe block
static constexpr int NVFE = 2 * BN_TOT / TI;   // 512 vfe blocks
static constexpr float EPSF = 1e-8f;

__host__ __device__ constexpr int gidx(int a, int b) {  // a < b
    return a * 7 - a * (a - 1) / 2 + (b - a - 1);
}

// agent-scope coherent ops (cross-XCD visibility verified R11/R12, absmax 0.0)
__device__ __forceinline__ void ast(float* p, float v) {
    __hip_atomic_store(p, v, __ATOMIC_RELAXED, __HIP_MEMORY_SCOPE_AGENT);
}
__device__ __forceinline__ float ald(const float* p) {
    return __hip_atomic_load(const_cast<float*>(p), __ATOMIC_RELAXED,
                             __HIP_MEMORY_SCOPE_AGENT);
}

// ---- Kernel 0: E_n = exp5(M(phi_n)); dual layout; also zeroes ctr --------
// E  [n][64]  row-major   (E_i reads: contiguous per block)
// ET [k][1024] transposed (E_j reads: lane-coalesced)
__global__ __launch_bounds__(256) void exp_kernel(
    const float* __restrict__ phi, float* __restrict__ E,
    float* __restrict__ ET, unsigned int* __restrict__ ctr) {
    if (blockIdx.x == 0 && threadIdx.x == 0)
        __hip_atomic_store(ctr, 0u, __ATOMIC_RELAXED, __HIP_MEMORY_SCOPE_AGENT);

    const int wid  = threadIdx.x >> 6;
    const int lane = threadIdx.x & 63;
    const int n0   = blockIdx.x << 2;
    const int n    = n0 + wid;                  // row in [0,1024)
    const int p    = lane >> 3, q = lane & 7;

    const float pv = (lane < DG) ? phi[(size_t)n * DG + lane] : 0.0f;
    const int  idx = (p < q) ? gidx(p, q) : ((p > q) ? gidx(q, p) : 0);
    const float sgn = (p < q) ? 1.0f : ((p > q) ? -1.0f : 0.0f);
    const float a = sgn * __shfl(pv, idx);      // A[p][q]

    float P = a;                                 // running power A^k
    float R = ((p == q) ? 1.0f : 0.0f) + a;      // I + A
    const float invk[4] = {0.5f, 1.0f/3.0f, 0.25f, 0.2f};
#pragma unroll
    for (int k = 0; k < 4; ++k) {                // orders 2..5
        float np = 0.0f;
#pragma unroll
        for (int r8 = 0; r8 < 8; ++r8) {
            np += __shfl(P, (lane & 56) + r8) * __shfl(a, (r8 << 3) + (lane & 7));
        }
        P = np * invk[k];
        R += P;
    }
    E[(size_t)n * 64 + lane] = R;                // kernel boundary = visibility

    __shared__ float ls[4][64];
    ls[wid][lane] = R;
    __syncthreads();
    const int k  = threadIdx.x >> 2;             // element 0..63
    const int dn = threadIdx.x & 3;              // row offset 0..3
    ET[(size_t)k * BN_TOT + n0 + dn] = ls[dn][k];
}

// ---- Kernel 1: pair work + last-block final reduce (no 3rd node) ---------
// block = (i-group of TI rows) x (j-half); 1 j/thread; ej reused for TI rows.
__global__ __launch_bounds__(256, 4) void vfe_kernel(
    const float* __restrict__ mu, const float* __restrict__ sigma,
    const float* __restrict__ E, const float* __restrict__ ET,
    float* __restrict__ s0_arr, float* __restrict__ s1_arr,
    unsigned int* __restrict__ ctr, float* __restrict__ out) {
    const int bid  = blockIdx.x;        // [0, 512)
    const int ig   = bid >> 1;          // i-group [0,256)
    const int half = bid & 1;
    const int i0   = ig << 2;           // first row (TI | 512: batch intact)
    const int base = i0 & ~511;         // b*512
    const int tid  = threadIdx.x;
    const int wid  = tid >> 6;
    const int gj   = base + (half << 8) + tid;

    __shared__ float shE[TI * 64];
    __shared__ float sh[TI][4][2];
    __shared__ float shf[4];
    __shared__ int   sh_last;

    // ---- per-thread j loads ----
    float muj[GD], rcj[GD], ldj;
    {
        const float4* p4 = reinterpret_cast<const float4*>(mu + (size_t)gj * GD);
        float4 v0 = p4[0], v1 = p4[1];
        muj[0]=v0.x; muj[1]=v0.y; muj[2]=v0.z; muj[3]=v0.w;
        muj[4]=v1.x; muj[5]=v1.y; muj[6]=v1.z; muj[7]=v1.w;
    }
    {
        const float4* p4 = reinterpret_cast<const float4*>(sigma + (size_t)gj * GD);
        float4 v0 = p4[0], v1 = p4[1];
        float s[GD] = {v0.x, v0.y, v0.z, v0.w, v1.x, v1.y, v1.z, v1.w};
        float prod = 1.0f;
#pragma unroll
        for (int k = 0; k < GD; ++k) {
            const float sp = s[k] + EPSF;
            rcj[k] = __builtin_amdgcn_rcpf(sp);
            prod *= sp;
        }
        ldj = __logf(prod);   // one log (validated R7-R12, absmax 0)
    }

    // ---- E_j row -> registers (lane-coalesced); E_i block -> LDS ----
    float ej[64];
#pragma unroll
    for (int k = 0; k < 64; ++k) ej[k] = ET[(size_t)k * BN_TOT + gj];
    shE[tid] = E[(size_t)i0 * 64 + tid];
    __syncthreads();

#pragma unroll 1
    for (int ii = 0; ii < TI; ++ii) {
        const int row = i0 + ii;
        const float* Ei   = &shE[ii * 64];            // LDS broadcast
        const float* mrow = mu + (size_t)row * GD;    // uniform input
        const float* srow = sigma + (size_t)row * GD; // uniform input

        // t = E_i * mu_j
        float t[GD];
#pragma unroll
        for (int p = 0; p < GD; ++p) {
            float tp = 0.0f;
#pragma unroll
            for (int q = 0; q < GD; ++q) tp = fmaf(Ei[(p << 3) + q], muj[q], tp);
            t[p] = tp;
        }
        // r = E_j^T * t
        float r[GD] = {0,0,0,0,0,0,0,0};
#pragma unroll
        for (int p = 0; p < GD; ++p) {
            const float tp = t[p];
#pragma unroll
            for (int c = 0; c < GD; ++c) r[c] = fmaf(ej[(p << 3) + c], tp, r[c]);
        }

        // klb = kl + 0.5*ld_i (uniform shift; corrected in the tail)
        float acc = 0.0f;
#pragma unroll
        for (int k = 0; k < GD; ++k) {
            const float df = r[k] - mrow[k];
            acc += (srow[k] + df * df) * rcj[k];
        }
        const float klb = 0.5f * (acc - 8.0f + ldj);

        // raw softmax partial (no max pass: diag kl~0, validated R5-R12)
        const float e  = __expf(-klb);
        float s0 = e;
        float s1 = klb * e;
#pragma unroll
        for (int off = 32; off > 0; off >>= 1) {
            s0 += __shfl_xor(s0, off);
            s1 += __shfl_xor(s1, off);
        }
        if ((tid & 63) == 0) {
            sh[ii][wid][0] = s0;
            sh[ii][wid][1] = s1;
        }
    }
    __syncthreads();
    if (tid < TI * 2) {
        const int ii = tid >> 1, c = tid & 1;
        const float v = sh[ii][0][c] + sh[ii][1][c] + sh[ii][2][c] + sh[ii][3][c];
        float* dst = c ? s1_arr : s0_arr;
        ast(&dst[(size_t)(i0 + ii) * 2 + half], v);
    }

    // ---- tail: last arriving block does the final reduce (pattern: R12) ----
    __syncthreads();   // partial ast-stores issued before the arrive
    if (tid == 0) {
        const unsigned int old =
            __hip_atomic_fetch_add(ctr, 1u, __ATOMIC_ACQ_REL,
                                   __HIP_MEMORY_SCOPE_AGENT);
        sh_last = (old == (unsigned int)(NVFE - 1)) ? 1 : 0;
    }
    __syncthreads();
    if (sh_last) {
        float v = 0.0f;
#pragma unroll
        for (int c = 0; c < 4; ++c) {
            const int r = tid + (c << 8);   // rows tid, +256, +512, +768
            const float S0 = ald(&s0_arr[2*r]) + ald(&s0_arr[2*r + 1]);
            const float S1 = ald(&s1_arr[2*r]) + ald(&s1_arr[2*r + 1]);

            float prod = 1.0f, ssum = 0.f, msum = 0.f;
#pragma unroll
            for (int k = 0; k < GD; ++k) {
                const float s  = sigma[(size_t)r * GD + k];
                const float mm = mu[(size_t)r * GD + k];
                prod *= (s + EPSF);
                ssum += s;
                msum += mm * mm;
            }
            const float ld = __logf(prod);
            const float f_align = S1 / S0 - 0.5f * ld;
            // -entropy + 0.1*kl_prior ; K*log(2*pi*e) = 22.703016531274763
            const float cterm = -0.5f * (22.70301653127476f + ld)
                              + 0.05f * (ssum + msum - 8.0f - ld);
            v += cterm + f_align;
        }
#pragma unroll
        for (int off = 32; off > 0; off >>= 1) v += __shfl_xor(v, off);
        if ((tid & 63) == 0) shf[wid] = v;
        __syncthreads();
        if (tid == 0)
            out[0] = (shf[0] + shf[1] + shf[2] + shf[3]) * (1.0f / (float)BN_TOT);
    }
}

extern "C" void kernel_launch(void* const* d_in, const int* in_sizes, int n_in,
                              void* d_out, int out_size, void* d_ws, size_t ws_size,
                              hipStream_t stream) {
    const float* mu    = (const float*)d_in[0];
    const float* sigma = (const float*)d_in[1];
    const float* phi   = (const float*)d_in[2];
    float* out = (float*)d_out;
    float* ws  = (float*)d_ws;

    float*        E      = ws;            // 65536 floats (row-major)
    float*        ET     = ws + 65536;    // 65536 floats (transposed)
    float*        s0_arr = ws + 131072;   // 2048
    float*        s1_arr = ws + 133120;   // 2048
    unsigned int* ctr    = (unsigned int*)(ws + 135168);  // 1 uint

    exp_kernel<<<256, 256, 0, stream>>>(phi, E, ET, ctr);
    vfe_kernel<<<NVFE, 256, 0, stream>>>(mu, sigma, E, ET, s0_arr, s1_arr, ctr, out);
}

// Round 14
// 17.824 us; speedup vs baseline: 7.0174x; 1.4857x over previous
//
#include <hip/hip_runtime.h>
#include <math.h>

static constexpr int GD  = 8;       // GAUGE_DIM
static constexpr int DG  = 28;      // dim of so(8)
static constexpr int BN_TOT = 1024; // B*N
static constexpr int TI  = 4;       // rows per block
static constexpr int NB  = BN_TOT / TI;   // 256 blocks
static constexpr float EPSF = 1e-8f;

__host__ __device__ constexpr int gidx(int a, int b) {  // a < b
    return a * 7 - a * (a - 1) / 2 + (b - a - 1);
}

// ---- Kernel 1: fully fused. Block = 4 rows x all 512 j's (512 threads).
// Each THREAD computes its own E_j = exp5(M(phi_j)) serially in registers
// (pure FMA, no shuffles/LDS) -- 128x redundant across blocks but ~3.5us
// chip-wide, cheaper than a kernel boundary + global E round-trip (R10).
// E_i comes from 1KB LDS: the 4 "diagonal" threads publish their own E.
// Full row softmax completes in-block -> node 2 is a trivial 1024-sum.
__global__ __launch_bounds__(512, 2) void fused_kernel(
    const float* __restrict__ mu, const float* __restrict__ sigma,
    const float* __restrict__ phi,
    float* __restrict__ s0_arr, float* __restrict__ s1_arr) {
    const int bid  = blockIdx.x;      // [0,256)
    const int tid  = threadIdx.x;     // [0,512)
    const int wid  = tid >> 6;
    const int i0   = bid * TI;        // first row
    const int base = i0 & ~511;       // batch base (TI | 512)
    const int il0  = i0 - base;       // rows' offset within batch
    const int gj   = base + tid;      // this thread's j (full batch coverage)

    __shared__ float shEi[TI][64];    // E_i for the block's 4 rows
    __shared__ float sh[TI][8][2];    // per-wave softmax partials

    // ---- load phi_j ----
    float pj[DG];
    {
        const float4* p4 = reinterpret_cast<const float4*>(phi + (size_t)gj * DG);
#pragma unroll
        for (int t = 0; t < 7; ++t) {
            float4 v = p4[t];
            pj[4*t] = v.x; pj[4*t+1] = v.y; pj[4*t+2] = v.z; pj[4*t+3] = v.w;
        }
    }

    // A[q][c] from flat so(8) coords, sign folded at compile time
#define AJ(q_, c_) ((q_) == (c_) ? 0.0f : ((q_) < (c_) ? pj[gidx((q_),(c_))] : -pj[gidx((c_),(q_))]))

    // ---- E_j = I + A + A^2/2! + ... + A^5/5!  (matches MAX_TERMS=6) ----
    // All static indices -> registers (rule #20). P,res = 128 regs + pj 28.
    float P[64], res[64];
#pragma unroll
    for (int p = 0; p < 8; ++p)
#pragma unroll
        for (int c = 0; c < 8; ++c) {
            const float a = AJ(p, c);
            P[p*8+c]   = a;
            res[p*8+c] = ((p == c) ? 1.0f : 0.0f) + a;
        }
    const float invk[4] = {0.5f, 1.0f/3.0f, 0.25f, 0.2f};
#pragma unroll
    for (int k = 0; k < 4; ++k) {     // orders 2..5
        float Pn[64];
#pragma unroll
        for (int p = 0; p < 8; ++p)
#pragma unroll
            for (int c = 0; c < 8; ++c) {
                float s = 0.0f;
#pragma unroll
                for (int q = 0; q < 8; ++q) {
                    if (q == c) continue;           // A[c][c] == 0
                    s = fmaf(P[p*8+q], AJ(q, c), s);
                }
                Pn[p*8+c] = s * invk[k];
            }
#pragma unroll
        for (int e = 0; e < 64; ++e) { P[e] = Pn[e]; res[e] += Pn[e]; }
    }
#undef AJ

    // ---- the 4 diagonal threads publish their E as E_i ----
    if (tid >= il0 && tid < il0 + TI) {
        const int ii = tid - il0;
#pragma unroll
        for (int e = 0; e < 64; ++e) shEi[ii][e] = res[e];
    }

    // ---- j-side loads (pj now dead; registers recycle) ----
    float muj[GD], rcj[GD], ldj;
    {
        const float4* p4 = reinterpret_cast<const float4*>(mu + (size_t)gj * GD);
        float4 v0 = p4[0], v1 = p4[1];
        muj[0]=v0.x; muj[1]=v0.y; muj[2]=v0.z; muj[3]=v0.w;
        muj[4]=v1.x; muj[5]=v1.y; muj[6]=v1.z; muj[7]=v1.w;
    }
    {
        const float4* p4 = reinterpret_cast<const float4*>(sigma + (size_t)gj * GD);
        float4 v0 = p4[0], v1 = p4[1];
        float s[GD] = {v0.x, v0.y, v0.z, v0.w, v1.x, v1.y, v1.z, v1.w};
        float prod = 1.0f;
#pragma unroll
        for (int k = 0; k < GD; ++k) {
            const float sp = s[k] + EPSF;
            rcj[k] = __builtin_amdgcn_rcpf(sp);
            prod *= sp;
        }
        ldj = __logf(prod);   // one log (validated R7-R13, absmax 0)
    }
    __syncthreads();

    // ---- pair phase: 4 rows, E_j register-resident ----
#pragma unroll 1
    for (int ii = 0; ii < TI; ++ii) {
        const int row = i0 + ii;
        const float* mrow = mu + (size_t)row * GD;     // uniform
        const float* srow = sigma + (size_t)row * GD;  // uniform

        // t = E_i * mu_j   (E_i via LDS broadcast reads)
        float t[GD];
#pragma unroll
        for (int p = 0; p < 8; ++p) {
            float tp = 0.0f;
#pragma unroll
            for (int q = 0; q < 8; ++q) tp = fmaf(shEi[ii][p*8+q], muj[q], tp);
            t[p] = tp;
        }
        // r = E_j^T * t    (own registers, pure FMA)
        float r[GD] = {0,0,0,0,0,0,0,0};
#pragma unroll
        for (int p = 0; p < 8; ++p) {
            const float tp = t[p];
#pragma unroll
            for (int c = 0; c < 8; ++c) r[c] = fmaf(res[p*8+c], tp, r[c]);
        }

        // klb = kl + 0.5*ld_i (uniform shift; corrected in reduce kernel)
        float acc = 0.0f;
#pragma unroll
        for (int k = 0; k < GD; ++k) {
            const float df = r[k] - mrow[k];
            acc += (srow[k] + df * df) * rcj[k];
        }
        const float klb = 0.5f * (acc - 8.0f + ldj);

        // raw softmax partial (no max pass: diag kl~0, validated R5-R13)
        const float e  = __expf(-klb);
        float s0 = e;
        float s1 = klb * e;
#pragma unroll
        for (int off = 32; off > 0; off >>= 1) {
            s0 += __shfl_xor(s0, off);
            s1 += __shfl_xor(s1, off);
        }
        if ((tid & 63) == 0) { sh[ii][wid][0] = s0; sh[ii][wid][1] = s1; }
    }
    __syncthreads();
    if (tid < TI * 2) {
        const int ii = tid >> 1, c = tid & 1;
        float v = 0.0f;
#pragma unroll
        for (int w = 0; w < 8; ++w) v += sh[ii][w][c];
        (c ? s1_arr : s0_arr)[i0 + ii] = v;
    }
}

// ---- Kernel 2: per-row constants + final mean (R6 reduce, full sums) ----
__global__ __launch_bounds__(1024) void reduce_kernel(
    const float* __restrict__ mu, const float* __restrict__ sigma,
    const float* __restrict__ s0_arr, const float* __restrict__ s1_arr,
    float* __restrict__ out) {
    __shared__ float sh[16];
    const int i = threadIdx.x;   // row in [0,1024)

    const float S0 = s0_arr[i];
    const float S1 = s1_arr[i];

    float prod = 1.0f, ssum = 0.f, msum = 0.f;
#pragma unroll
    for (int k = 0; k < GD; ++k) {
        const float s  = sigma[(size_t)i * GD + k];
        const float mm = mu[(size_t)i * GD + k];
        prod *= (s + EPSF);
        ssum += s;
        msum += mm * mm;
    }
    const float ld = __logf(prod);
    const float f_align = S1 / S0 - 0.5f * ld;
    // -entropy + 0.1*kl_prior ; K*log(2*pi*e) = 22.703016531274763
    const float cterm = -0.5f * (22.70301653127476f + ld)
                      + 0.05f * (ssum + msum - 8.0f - ld);
    float v = cterm + f_align;

#pragma unroll
    for (int off = 32; off > 0; off >>= 1) v += __shfl_xor(v, off);
    if ((i & 63) == 0) sh[i >> 6] = v;
    __syncthreads();
    if (i == 0) {
        float tot = 0.f;
#pragma unroll
        for (int w = 0; w < 16; ++w) tot += sh[w];
        out[0] = tot * (1.0f / (float)BN_TOT);
    }
}

extern "C" void kernel_launch(void* const* d_in, const int* in_sizes, int n_in,
                              void* d_out, int out_size, void* d_ws, size_t ws_size,
                              hipStream_t stream) {
    const float* mu    = (const float*)d_in[0];
    const float* sigma = (const float*)d_in[1];
    const float* phi   = (const float*)d_in[2];
    float* out = (float*)d_out;
    float* ws  = (float*)d_ws;

    float* s0_arr = ws;          // 1024 floats
    float* s1_arr = ws + 1024;   // 1024

    fused_kernel<<<NB, 512, 0, stream>>>(mu, sigma, phi, s0_arr, s1_arr);
    reduce_kernel<<<1, 1024, 0, stream>>>(mu, sigma, s0_arr, s1_arr, out);
}